// Round 6
// baseline (328.298 us; speedup 1.0000x reference)
//
#include <hip/hip_runtime.h>

// 3x3 valid conv (NCHW/OIHW) + bias + relu(y)*min(y+3,6)/6, fp32.
// x: (N=4096, C=3, 32, 32), w: (16, 3, 3, 3), out: (N, 16, 30, 30).
//
// Round 10 design: NO LDS AT ALL.
//  - R4-R9 swapped every block component (weight path, store path, barrier
//    count, LDS op count, occupancy) with <=10% effect. The one untouched
//    component: the staging+commit lockstep itself. R10 deletes it: x is
//    read directly from global (L1/L2-resident; image is block-private
//    12KB, reuse 4.3x) as one dwordx4 + one dwordx2 per (ic,kh) per thread.
//    Zero LDS, zero barriers, zero inter-wave coupling -> 16 independent
//    free-running waves per CU, phase-drifted demand instead of bursts.
//  - Thread = horizontal 4-px group (g = oh*8 + ow/4, 240 slots), as R9.
//  - FMA order identical to R9 (ic->kh->kw, xv[k+kw]) -> bitwise-identical
//    stored output. Tail group (ow=28): its 2-col side-load is redirected
//    in-row (cols 30,31 instead of 32,33); those values feed only acc[2..3]
//    which the tail group never stores -> no OOB access, same results.
//  - Keep: SGPR weight path (s_load, v_fmac v,s,v), direct float2 stores
//    from acc regs, 4 img/block (grid 1024 = exactly 4 blocks/CU),
//    __launch_bounds__(256,4) (~90 VGPR, no spill; R5 lesson).

#define IMGS 4

__global__ __launch_bounds__(256, 4) void conv3x3_hswish(
    const float* __restrict__ x,
    const float* __restrict__ w,
    const float* __restrict__ bias,
    float* __restrict__ out)
{
    const int tid  = threadIdx.x;
    const int img0 = blockIdx.x * IMGS;

    // Slot: g = oh*8 + ow/4; threads 240..255 shadow slot 239 (no stores).
    const int g  = tid < 240 ? tid : 239;
    const int oh = g >> 3;
    const int ow = (g & 7) << 2;            // 0,4,...,28
    const bool active = tid < 240;
    const bool full   = ow < 28;            // ow=28 group: only px 0,1 valid
    // Side-load offset: cols ow+4,ow+5 normally; tail group reads cols
    // ow+2,ow+3 instead (in-row, in-bounds; feeds only discarded accs).
    const int e2 = full ? 4 : 2;

    // Bias via scalar path (uniform -> SGPR).
    float bb[16];
    #pragma unroll
    for (int oc = 0; oc < 16; ++oc) bb[oc] = bias[oc];

    #pragma unroll 1
    for (int im = 0; im < IMGS; ++im) {
        const float* xi = x + (size_t)(img0 + im) * 3072 + oh * 32 + ow;

        float acc[4][16];
        #pragma unroll
        for (int k = 0; k < 4; ++k)
            #pragma unroll
            for (int oc = 0; oc < 16; ++oc) acc[k][oc] = 0.f;

        // Hot loop: dynamic ic, static (kh,kw); weights via s_load/SGPR,
        // x via direct global loads (L1/L2 hits after first touch).
        #pragma unroll 1
        for (int ic = 0; ic < 3; ++ic) {
            const float* __restrict__ wq = w + ic * 9;
            const float* xr = xi + (ic << 10);
            #pragma unroll
            for (int kh = 0; kh < 3; ++kh) {
                const float4 v4 = *(const float4*)(xr + kh * 32);
                const float2 v2 = *(const float2*)(xr + kh * 32 + e2);
                const float xv[6] = {v4.x, v4.y, v4.z, v4.w, v2.x, v2.y};
                #pragma unroll
                for (int kw = 0; kw < 3; ++kw) {
                    float ws[16];
                    #pragma unroll
                    for (int oc = 0; oc < 16; ++oc)
                        ws[oc] = wq[oc * 27 + kh * 3 + kw];   // uniform->SGPR
                    #pragma unroll
                    for (int k = 0; k < 4; ++k) {
                        const float xx = xv[k + kw];          // static index
                        #pragma unroll
                        for (int oc = 0; oc < 16; ++oc)
                            acc[k][oc] = fmaf(xx, ws[oc], acc[k][oc]);
                    }
                }
            }
        }

        // Epilogue: bias + hardswish*relu, direct float2 stores from regs.
        float* outb = out + (size_t)(img0 + im) * 14400 + oh * 30 + ow;
        if (active) {
            #pragma unroll
            for (int oc = 0; oc < 16; ++oc) {
                const float y0 = acc[0][oc] + bb[oc];
                const float y1 = acc[1][oc] + bb[oc];
                float2 r01;
                r01.x = fmaxf(y0, 0.f) * fminf(fmaf(y0, 1.f / 6.f, 0.5f), 1.f);
                r01.y = fmaxf(y1, 0.f) * fminf(fmaf(y1, 1.f / 6.f, 0.5f), 1.f);
                *(float2*)(outb + oc * 900) = r01;
                if (full) {
                    const float y2 = acc[2][oc] + bb[oc];
                    const float y3 = acc[3][oc] + bb[oc];
                    float2 r23;
                    r23.x = fmaxf(y2, 0.f) * fminf(fmaf(y2, 1.f / 6.f, 0.5f), 1.f);
                    r23.y = fmaxf(y3, 0.f) * fminf(fmaf(y3, 1.f / 6.f, 0.5f), 1.f);
                    *(float2*)(outb + oc * 900 + 2) = r23;
                }
            }
        }
    }
}

extern "C" void kernel_launch(void* const* d_in, const int* in_sizes, int n_in,
                              void* d_out, int out_size, void* d_ws, size_t ws_size,
                              hipStream_t stream) {
    const float* x    = (const float*)d_in[0];
    const float* w    = (const float*)d_in[1];
    const float* bias = (const float*)d_in[2];
    float* out        = (float*)d_out;

    const int N = in_sizes[0] / (3 * 32 * 32);  // 4096
    conv3x3_hswish<<<N / IMGS, 256, 0, stream>>>(x, w, bias, out);
}